// Round 1
// baseline (982.988 us; speedup 1.0000x reference)
//
#include <hip/hip_runtime.h>

// RecursiveNN: perfect binary tree over 8192 leaves (16383 nodes), EMBED=512.
// Level-parallel evaluation: leaves = embedding gather+relu; each internal
// level h (2^(13-h) nodes) is a GEMM  C[M,512] = relu([Hl;Hr][M,1024] @ W^T + bW).
// Final projection: out[n,c] = H[n,:] . P[c,:] + bP[c].
//
// ws layout: H (16384 rows x 512 f32 = 33.5 MB) | level lists (16384 int) | counters.

#define EMBED 512
#define K2    1024
#define BM 64
#define BN 64
#define BK 16

__device__ __forceinline__ float relu_f(float x) { return fmaxf(x, 0.0f); }

// ---------------------------------------------------------------------------
// Build per-level node lists. Height found by walking the left spine
// (children precede parents in post-order, left[] of a leaf is unused).
__global__ void build_levels(const int* __restrict__ is_leaf,
                             const int* __restrict__ left,
                             int* __restrict__ list, int* __restrict__ cnt,
                             int nNodes, int nLeaves, int L)
{
    int i = blockIdx.x * blockDim.x + threadIdx.x;
    if (i >= nNodes) return;
    int h = 0, j = i;
    while (!is_leaf[j]) { j = left[j]; ++h; }   // <= 13 iterations
    int off = (h == 0) ? 0 : (2 * nLeaves - (1 << (L + 1 - h)));
    int pos = atomicAdd(&cnt[h], 1);
    list[off + pos] = i;
}

// ---------------------------------------------------------------------------
// Leaves: H[node] = relu(emb[word[node]]). One wave (64 lanes) per leaf,
// 2x float4 per lane = 512 floats.
__global__ void leaf_kernel(const float* __restrict__ emb,
                            const int* __restrict__ word,
                            const int* __restrict__ list,
                            float* __restrict__ H, int nLeaves)
{
    int t = blockIdx.x * blockDim.x + threadIdx.x;
    int leaf = t >> 6;
    int lane = t & 63;
    if (leaf >= nLeaves) return;
    int node = list[leaf];                 // level-0 list at offset 0
    int wd = word[node];
    const float4* src = (const float4*)(emb + (size_t)wd * EMBED);
    float4* dst = (float4*)(H + (size_t)node * EMBED);
#pragma unroll
    for (int i = 0; i < 2; ++i) {
        float4 v = src[lane + 64 * i];
        v.x = relu_f(v.x); v.y = relu_f(v.y); v.z = relu_f(v.z); v.w = relu_f(v.w);
        dst[lane + 64 * i] = v;
    }
}

// ---------------------------------------------------------------------------
// One tree level: for m in [0,M): node n = list[off+m],
//   H[n, :] = relu( concat(H[left[n]], H[right[n]]) @ W^T + bW )
// Tiled fp32 GEMM: BM=64 x BN=64 tile, BK=16, 256 threads, 4x4 per thread.
__global__ __launch_bounds__(256)
void gemm_level(const float* __restrict__ H, const float* __restrict__ W,
                const float* __restrict__ bW, const int* __restrict__ list,
                const int* __restrict__ left, const int* __restrict__ right,
                float* __restrict__ Hout, int off, int M)
{
    __shared__ __align__(16) float Xs[BK][BM + 4];
    __shared__ __align__(16) float Ws[BK][BN + 4];
    __shared__ int rowL[BM], rowR[BM], nodeIdx[BM];

    int tid = threadIdx.x;
    int m0 = blockIdx.x * BM;
    int n0 = blockIdx.y * BN;

    if (tid < BM) {
        int m = m0 + tid;
        int mc = (m < M) ? m : (M - 1);    // clamp: loads valid, stores guarded
        int n = list[off + mc];
        nodeIdx[tid] = n;
        rowL[tid] = left[n]  * EMBED;
        rowR[tid] = right[n] * EMBED;
    }
    __syncthreads();

    float acc[4][4] = {};
    int lm = tid >> 2;            // 0..63 : tile row being loaded
    int lk = (tid & 3) * 4;       // 0,4,8,12 : k offset within BK

    for (int k0 = 0; k0 < K2; k0 += BK) {
        // stage X tile (gathered from the two children rows; BK=16 divides 512
        // so a tile never straddles the child boundary)
        int base = (k0 < EMBED) ? (rowL[lm] + k0 + lk)
                                : (rowR[lm] + k0 + lk - EMBED);
        float4 xv = *(const float4*)(H + base);
        Xs[lk + 0][lm] = xv.x; Xs[lk + 1][lm] = xv.y;
        Xs[lk + 2][lm] = xv.z; Xs[lk + 3][lm] = xv.w;
        // stage W tile: W[(n0+lm)][k0+lk .. +3]
        float4 wv = *(const float4*)(W + (size_t)(n0 + lm) * K2 + k0 + lk);
        Ws[lk + 0][lm] = wv.x; Ws[lk + 1][lm] = wv.y;
        Ws[lk + 2][lm] = wv.z; Ws[lk + 3][lm] = wv.w;
        __syncthreads();

        int tx = tid & 15, ty = tid >> 4;
#pragma unroll
        for (int k = 0; k < BK; ++k) {
            float4 a = *(const float4*)&Xs[k][ty * 4];
            float4 b = *(const float4*)&Ws[k][tx * 4];
            float av[4] = {a.x, a.y, a.z, a.w};
            float bv[4] = {b.x, b.y, b.z, b.w};
#pragma unroll
            for (int i = 0; i < 4; ++i)
#pragma unroll
                for (int j = 0; j < 4; ++j)
                    acc[i][j] = fmaf(av[i], bv[j], acc[i][j]);
        }
        __syncthreads();
    }

    int tx = tid & 15, ty = tid >> 4;
#pragma unroll
    for (int i = 0; i < 4; ++i) {
        int m = m0 + ty * 4 + i;
        if (m < M) {
            int node = nodeIdx[ty * 4 + i];
            int d = n0 + tx * 4;
            float4 r;
            r.x = relu_f(acc[i][0] + bW[d + 0]);
            r.y = relu_f(acc[i][1] + bW[d + 1]);
            r.z = relu_f(acc[i][2] + bW[d + 2]);
            r.w = relu_f(acc[i][3] + bW[d + 3]);
            *(float4*)(Hout + (size_t)node * EMBED + d) = r;
        }
    }
}

// ---------------------------------------------------------------------------
// Projection: out[n, c] = H[n,:] . P[c,:] + bP[c]. One wave per node,
// 8 floats/lane, shuffle reduction over 64 lanes for the 5 classes.
__global__ __launch_bounds__(256)
void out_kernel(const float* __restrict__ H, const float* __restrict__ P,
                const float* __restrict__ bP, float* __restrict__ out, int nNodes)
{
    int t = blockIdx.x * blockDim.x + threadIdx.x;
    int node = t >> 6;
    int lane = t & 63;
    if (node >= nNodes) return;
    const float4* h4 = (const float4*)(H + (size_t)node * EMBED);
    float4 h0 = h4[lane], h1 = h4[lane + 64];
    float s[5];
#pragma unroll
    for (int c = 0; c < 5; ++c) {
        const float4* p4 = (const float4*)(P + c * EMBED);
        float4 p0 = p4[lane], p1 = p4[lane + 64];
        s[c] = h0.x * p0.x + h0.y * p0.y + h0.z * p0.z + h0.w * p0.w
             + h1.x * p1.x + h1.y * p1.y + h1.z * p1.z + h1.w * p1.w;
    }
#pragma unroll
    for (int o = 32; o > 0; o >>= 1)
#pragma unroll
        for (int c = 0; c < 5; ++c)
            s[c] += __shfl_down(s[c], o, 64);
    if (lane == 0) {
#pragma unroll
        for (int c = 0; c < 5; ++c)
            out[(size_t)node * 5 + c] = s[c] + bP[c];
    }
}

// ---------------------------------------------------------------------------
extern "C" void kernel_launch(void* const* d_in, const int* in_sizes, int n_in,
                              void* d_out, int out_size, void* d_ws, size_t ws_size,
                              hipStream_t stream)
{
    const int*   is_leaf = (const int*)d_in[0];
    const int*   word    = (const int*)d_in[1];
    const int*   left    = (const int*)d_in[2];
    const int*   right   = (const int*)d_in[3];
    const float* emb     = (const float*)d_in[4];
    const float* W       = (const float*)d_in[5];
    const float* bW      = (const float*)d_in[6];
    const float* P       = (const float*)d_in[7];
    const float* bP      = (const float*)d_in[8];
    float* out = (float*)d_out;

    int nNodes  = in_sizes[0];            // 16383
    int nLeaves = (nNodes + 1) / 2;       // 8192
    int L = 0;
    while ((1 << L) < nLeaves) ++L;       // 13

    float* H  = (float*)d_ws;
    int* list = (int*)((char*)d_ws + (size_t)(nNodes + 1) * EMBED * sizeof(float));
    int* cnt  = list + (nNodes + 1);

    hipMemsetAsync(cnt, 0, 32 * sizeof(int), stream);
    build_levels<<<dim3((nNodes + 255) / 256), dim3(256), 0, stream>>>(
        is_leaf, left, list, cnt, nNodes, nLeaves, L);
    leaf_kernel<<<dim3((nLeaves * 64 + 255) / 256), dim3(256), 0, stream>>>(
        emb, word, list, H, nLeaves);
    for (int h = 1; h <= L; ++h) {
        int M   = 1 << (L - h);
        int off = 2 * nLeaves - (1 << (L + 1 - h));
        dim3 grid((M + BM - 1) / BM, EMBED / BN);
        gemm_level<<<grid, dim3(256), 0, stream>>>(
            H, W, bW, list, left, right, H, off, M);
    }
    out_kernel<<<dim3((nNodes * 64 + 255) / 256), dim3(256), 0, stream>>>(
        H, P, bP, out, nNodes);
}

// Round 2
// 516.061 us; speedup vs baseline: 1.9048x; 1.9048x over previous
//
#include <hip/hip_runtime.h>

// RecursiveNN: perfect binary tree, 8192 leaves (post-order from _build_tree).
// Closed-form indexing (no build pass): node at height h, position m:
//   idx = ((m+1) << (h+1)) - 2 - popc(m);  left = idx - (1<<h);  right = idx - 1
// Numerics: H kept as fp16 hi+lo split (residual ~2^-22 rel); each level is
//   C = relu(X @ W^T + bW) via 3-term MFMA: Xh*Wh + Xh*Wl + Xl*Wh.
// W pre-split & repacked once into MFMA-B fragment layout -> all fragment
// loads are direct global (L1/L2 resident), no LDS, no barriers.
//
// mfma_f32_16x16x32_f16 layouts (HW-verified per guide):
//   A[m][k]: m = lane&15, k = (lane>>4)*8 + j   (8 halves / lane, contiguous k)
//   B[k][n]: n = lane&15, k = (lane>>4)*8 + j
//   C/D    : col = lane&15, row = (lane>>4)*4 + reg

#define EMBED 512
#define K2    1024

typedef _Float16 half8 __attribute__((ext_vector_type(8)));
typedef float    floatx4 __attribute__((ext_vector_type(4)));

__device__ __forceinline__ float relu_f(float x) { return fmaxf(x, 0.0f); }

// ---------------------------------------------------------------------------
// Split W (512x1024 f32) into fp16 hi/lo, repacked so a B-fragment for
// (n-tile T, k-step s) is 64 lanes x 16 B contiguous:
//   offset = T*16384 + s*512 + lane*8, lane = ((k>>3)&3)<<4 | (n&15)
__global__ __launch_bounds__(256)
void pack_w(const float* __restrict__ W,
            _Float16* __restrict__ Whp, _Float16* __restrict__ Wlp)
{
    int t = blockIdx.x * 256 + threadIdx.x;      // 65536 threads
    int n = t >> 7, kc = t & 127;                // kc: chunk of 8 k
    const float* src = W + (size_t)n * K2 + kc * 8;
    int s = kc >> 2, quad = kc & 3;
    int lane = (quad << 4) | (n & 15);
    size_t off = (size_t)(n >> 4) * 16384 + (size_t)s * 512 + (size_t)lane * 8;
    half8 hi, lo;
#pragma unroll
    for (int j = 0; j < 8; ++j) {
        float w = src[j];
        _Float16 h = (_Float16)w;
        hi[j] = h;
        lo[j] = (_Float16)(w - (float)h);
    }
    *(half8*)(Whp + off) = hi;
    *(half8*)(Wlp + off) = lo;
}

// ---------------------------------------------------------------------------
// Leaves: H[idx] = relu(emb[word[idx]]), split to fp16 hi/lo. Wave per leaf.
__global__ __launch_bounds__(256)
void leaf_kernel(const float* __restrict__ emb, const int* __restrict__ word,
                 _Float16* __restrict__ Hh, _Float16* __restrict__ Hl, int nLeaves)
{
    int t = blockIdx.x * 256 + threadIdx.x;
    int m = t >> 6, lane = t & 63;
    if (m >= nLeaves) return;
    int idx = 2 * m - __popc(m);                 // height-0 closed form
    int wd = word[idx];
    const float4* src = (const float4*)(emb + (size_t)wd * EMBED) + lane * 2;
    float4 a = src[0], b = src[1];
    float v[8] = {a.x, a.y, a.z, a.w, b.x, b.y, b.z, b.w};
    half8 hi, lo;
#pragma unroll
    for (int j = 0; j < 8; ++j) {
        float x = relu_f(v[j]);
        _Float16 h = (_Float16)x;
        hi[j] = h;
        lo[j] = (_Float16)(x - (float)h);
    }
    *(half8*)(Hh + (size_t)idx * EMBED + lane * 8) = hi;
    *(half8*)(Hl + (size_t)idx * EMBED + lane * 8) = lo;
}

// ---------------------------------------------------------------------------
// One tree level. Block = 4 waves; wave w owns rows mw..mw+15, cols n0..n0+63
// (4 n-tiles). 3-term split-fp16 MFMA, fragments loaded straight from global.
__global__ __launch_bounds__(256)
void gemm_level(_Float16* Hh, _Float16* Hl,
                const _Float16* __restrict__ Whp, const _Float16* __restrict__ Wlp,
                const float* __restrict__ bW, int h, int M)
{
    int tid = threadIdx.x;
    int wave = tid >> 6, lane = tid & 63;
    int quad = lane >> 4, r = lane & 15;
    int mw = (blockIdx.x * 4 + wave) * 16;

    // A-operand row for this lane (clamped; stores are guarded)
    int m = mw + r;
    if (m >= M) m = M - 1;
    int idx = ((m + 1) << (h + 1)) - 2 - __popc(m);
    int leftRow  = idx - (1 << h);
    int rightRow = idx - 1;
    const _Float16* pLh = Hh + (size_t)leftRow  * EMBED + quad * 8;
    const _Float16* pLl = Hl + (size_t)leftRow  * EMBED + quad * 8;
    const _Float16* pRh = Hh + (size_t)rightRow * EMBED + quad * 8;
    const _Float16* pRl = Hl + (size_t)rightRow * EMBED + quad * 8;
    const _Float16* pBh = Whp + (size_t)blockIdx.y * 4 * 16384 + lane * 8;
    const _Float16* pBl = Wlp + (size_t)blockIdx.y * 4 * 16384 + lane * 8;

    floatx4 acc[4];
#pragma unroll
    for (int nt = 0; nt < 4; ++nt) acc[nt] = (floatx4){0.f, 0.f, 0.f, 0.f};

#pragma unroll 4
    for (int s = 0; s < 32; ++s) {
        int k0 = s * 32;
        const _Float16* ah_p = (s < 16) ? (pLh + k0) : (pRh + k0 - EMBED);
        const _Float16* al_p = (s < 16) ? (pLl + k0) : (pRl + k0 - EMBED);
        half8 ah = *(const half8*)ah_p;
        half8 al = *(const half8*)al_p;
#pragma unroll
        for (int nt = 0; nt < 4; ++nt) {
            half8 bh = *(const half8*)(pBh + nt * 16384 + s * 512);
            half8 bl = *(const half8*)(pBl + nt * 16384 + s * 512);
            acc[nt] = __builtin_amdgcn_mfma_f32_16x16x32_f16(ah, bh, acc[nt], 0, 0, 0);
            acc[nt] = __builtin_amdgcn_mfma_f32_16x16x32_f16(ah, bl, acc[nt], 0, 0, 0);
            acc[nt] = __builtin_amdgcn_mfma_f32_16x16x32_f16(al, bh, acc[nt], 0, 0, 0);
        }
    }

    // Epilogue: C/D row = quad*4+reg, col = r. Bias + relu + fp16 hi/lo split.
    int n0 = blockIdx.y * 64;
#pragma unroll
    for (int nt = 0; nt < 4; ++nt) {
        int col = n0 + nt * 16 + r;
        float bw = bW[col];
#pragma unroll
        for (int reg = 0; reg < 4; ++reg) {
            int mm = mw + quad * 4 + reg;
            if (mm < M) {
                float v = relu_f(acc[nt][reg] + bw);
                _Float16 hi = (_Float16)v;
                _Float16 lo = (_Float16)(v - (float)hi);
                int nodeIdx = ((mm + 1) << (h + 1)) - 2 - __popc(mm);
                Hh[(size_t)nodeIdx * EMBED + col] = hi;
                Hl[(size_t)nodeIdx * EMBED + col] = lo;
            }
        }
    }
}

// ---------------------------------------------------------------------------
// Projection: out[n,c] = (Hh[n]+Hl[n]) . P[c] + bP[c]. Wave per node.
__global__ __launch_bounds__(256)
void out_kernel(const _Float16* __restrict__ Hh, const _Float16* __restrict__ Hl,
                const float* __restrict__ P, const float* __restrict__ bP,
                float* __restrict__ out, int nNodes)
{
    int t = blockIdx.x * 256 + threadIdx.x;
    int node = t >> 6, lane = t & 63;
    if (node >= nNodes) return;
    half8 hv = *(const half8*)(Hh + (size_t)node * EMBED + lane * 8);
    half8 lv = *(const half8*)(Hl + (size_t)node * EMBED + lane * 8);
    float hx[8];
#pragma unroll
    for (int j = 0; j < 8; ++j) hx[j] = (float)hv[j] + (float)lv[j];
    float s[5];
#pragma unroll
    for (int c = 0; c < 5; ++c) {
        const float* p = P + c * EMBED + lane * 8;
        float4 p0 = *(const float4*)p;
        float4 p1 = *(const float4*)(p + 4);
        s[c] = hx[0] * p0.x + hx[1] * p0.y + hx[2] * p0.z + hx[3] * p0.w
             + hx[4] * p1.x + hx[5] * p1.y + hx[6] * p1.z + hx[7] * p1.w;
    }
#pragma unroll
    for (int o = 32; o > 0; o >>= 1)
#pragma unroll
        for (int c = 0; c < 5; ++c)
            s[c] += __shfl_down(s[c], o, 64);
    if (lane == 0) {
#pragma unroll
        for (int c = 0; c < 5; ++c)
            out[(size_t)node * 5 + c] = s[c] + bP[c];
    }
}

// ---------------------------------------------------------------------------
extern "C" void kernel_launch(void* const* d_in, const int* in_sizes, int n_in,
                              void* d_out, int out_size, void* d_ws, size_t ws_size,
                              hipStream_t stream)
{
    const int*   word = (const int*)d_in[1];
    const float* emb  = (const float*)d_in[4];
    const float* W    = (const float*)d_in[5];
    const float* bW   = (const float*)d_in[6];
    const float* P    = (const float*)d_in[7];
    const float* bP   = (const float*)d_in[8];
    float* out = (float*)d_out;

    int nNodes  = in_sizes[0];            // 16383
    int nLeaves = (nNodes + 1) / 2;       // 8192
    int L = 0;
    while ((1 << L) < nLeaves) ++L;       // 13

    // ws: Hh | Hl (fp16, 16384 rows x 512) | Whp | Wlp (fp16 packed) ~ 36 MB
    _Float16* Hh  = (_Float16*)d_ws;
    _Float16* Hl  = Hh  + (size_t)(nNodes + 1) * EMBED;
    _Float16* Whp = Hl  + (size_t)(nNodes + 1) * EMBED;
    _Float16* Wlp = Whp + (size_t)EMBED * K2;

    pack_w<<<dim3(256), dim3(256), 0, stream>>>(W, Whp, Wlp);
    leaf_kernel<<<dim3((nLeaves * 64 + 255) / 256), dim3(256), 0, stream>>>(
        emb, word, Hh, Hl, nLeaves);
    for (int h = 1; h <= L; ++h) {
        int M = 1 << (L - h);
        dim3 grid((M + 63) / 64, EMBED / 64);
        gemm_level<<<grid, dim3(256), 0, stream>>>(Hh, Hl, Whp, Wlp, bW, h, M);
    }
    out_kernel<<<dim3((nNodes * 64 + 255) / 256), dim3(256), 0, stream>>>(
        Hh, Hl, P, bP, out, nNodes);
}

// Round 3
// 483.388 us; speedup vs baseline: 2.0335x; 1.0676x over previous
//
#include <hip/hip_runtime.h>

// RecursiveNN, perfect binary tree, 8192 leaves, EMBED=512.
// Closed-form post-order indexing: node at height h, position m:
//   idx = ((m+1)<<(h+1)) - 2 - popc(m);  left = idx - (1<<h);  right = idx - 1
// Numerics: fp16 hi+lo split H and W; 3-term MFMA (hh, hl, lh) => ~fp32 accuracy
// (measured absmax == fp32-reorder noise, 36x under threshold).
// Big levels (M>=128): LDS-staged GEMM, m97-style global_load_lds width=16,
//   block tile 64x128, 4 waves 2x2, each wave 2x4 16x16 MFMA tiles.
//   LDS layout IS the fragment layout -> ds_read_b128 conflict-free.
// Small levels (M<=64): fragment-direct kernel (latency-bound anyway).

#define EMBED 512
#define K2    1024
#define WOFF  (EMBED * K2)   // halves between Whp and Wlp (contiguous)

typedef _Float16 half8 __attribute__((ext_vector_type(8)));
typedef float    floatx4 __attribute__((ext_vector_type(4)));

__device__ __forceinline__ float relu_f(float x) { return fmaxf(x, 0.0f); }

#define GLDS16(gp, lp)                                                        \
    __builtin_amdgcn_global_load_lds(                                         \
        (const __attribute__((address_space(1))) void*)(gp),                  \
        (__attribute__((address_space(3))) void*)(lp), 16, 0, 0)

// ---------------------------------------------------------------------------
// Split W (512x1024 f32) into fp16 hi/lo, packed in MFMA-B fragment order:
// for n-tile T, k-step S: 1 KB contiguous, offset = T*16384 + S*512 + lane*8,
// lane = ((k>>3)&3)<<4 | (n&15).
__global__ __launch_bounds__(256)
void pack_w(const float* __restrict__ W,
            _Float16* __restrict__ Whp, _Float16* __restrict__ Wlp)
{
    int t = blockIdx.x * 256 + threadIdx.x;      // 65536 threads
    int n = t >> 7, kc = t & 127;                // kc: chunk of 8 k
    const float* src = W + (size_t)n * K2 + kc * 8;
    int s = kc >> 2, quad = kc & 3;
    int lane = (quad << 4) | (n & 15);
    size_t off = (size_t)(n >> 4) * 16384 + (size_t)s * 512 + (size_t)lane * 8;
    half8 hi, lo;
#pragma unroll
    for (int j = 0; j < 8; ++j) {
        float w = src[j];
        _Float16 h = (_Float16)w;
        hi[j] = h;
        lo[j] = (_Float16)(w - (float)h);
    }
    *(half8*)(Whp + off) = hi;
    *(half8*)(Wlp + off) = lo;
}

// ---------------------------------------------------------------------------
__global__ __launch_bounds__(256)
void leaf_kernel(const float* __restrict__ emb, const int* __restrict__ word,
                 _Float16* __restrict__ Hh, _Float16* __restrict__ Hl, int nLeaves)
{
    int t = blockIdx.x * 256 + threadIdx.x;
    int m = t >> 6, lane = t & 63;
    if (m >= nLeaves) return;
    int idx = 2 * m - __popc(m);
    int wd = word[idx];
    const float4* src = (const float4*)(emb + (size_t)wd * EMBED) + lane * 2;
    float4 a = src[0], b = src[1];
    float v[8] = {a.x, a.y, a.z, a.w, b.x, b.y, b.z, b.w};
    half8 hi, lo;
#pragma unroll
    for (int j = 0; j < 8; ++j) {
        float x = relu_f(v[j]);
        _Float16 h = (_Float16)x;
        hi[j] = h;
        lo[j] = (_Float16)(x - (float)h);
    }
    *(half8*)(Hh + (size_t)idx * EMBED + lane * 8) = hi;
    *(half8*)(Hl + (size_t)idx * EMBED + lane * 8) = lo;
}

// ---------------------------------------------------------------------------
// Big-level GEMM. Block 64 rows x 128 cols, 256 threads (4 waves, 2x2).
// K-loop: 16 chunks of BK=64. Per chunk, LDS holds A/B fragments for both
// k-steps (s2=0,1), hi+lo:
//   A slot (t,s2,hl)  t<4 : lds[((t*2+s2)*2+hl)*512]        16 slots, 16 KB
//   B slot (u,s2,hl)  u<8 : lds[8192 + ((u*2+s2)*2+hl)*512] 32 slots, 32 KB
// Each slot = 64 lanes x 16 B in fragment lane order, staged by ONE
// global_load_lds (per-lane gather on the global side for A).
__global__ __launch_bounds__(256)
void gemm_big(const _Float16* H,            // Hh base; Hl = H + hoff
              const _Float16* __restrict__ Wp,  // Whp; Wlp = Wp + WOFF
              const float* __restrict__ bW,
              _Float16* Hh, _Float16* Hl,
              int h, int M, int hoff)
{
    __shared__ _Float16 lds[48 * 512];          // 48 KB

    int tid = threadIdx.x;
    int wave = tid >> 6, lane = tid & 63;
    int q = lane >> 4, r = lane & 15;
    int wm = wave >> 1, wn = wave & 1;
    int bm0 = blockIdx.x * 64, bn0 = blockIdx.y * 128;

    // Staging addresses: wave stages A for m-tile t==wave.
    int ms = bm0 + wave * 16 + r;
    if (ms >= M) ms = M - 1;
    int node_s = ((ms + 1) << (h + 1)) - 2 - __popc(ms);
    int aL = (node_s - (1 << h)) * EMBED + q * 8;   // left child row, halves
    int aR = (node_s - 1) * EMBED + q * 8;          // right child row

    floatx4 acc[2][4];
#pragma unroll
    for (int i = 0; i < 2; ++i)
#pragma unroll
        for (int j = 0; j < 4; ++j) acc[i][j] = (floatx4){0.f, 0.f, 0.f, 0.f};

    for (int kc = 0; kc < 16; ++kc) {
        // ---- stage: 4 A-slots + 8 B-slots per wave (1 KB each)
        int abase = (kc < 8) ? (aL + kc * 64) : (aR + (kc - 8) * 64);
#pragma unroll
        for (int i = 0; i < 4; ++i) {           // i = s2*2 + hl
            int s2 = i >> 1, hl = i & 1;
            const _Float16* gp = H + abase + s2 * 32 + (hl ? hoff : 0);
            GLDS16(gp, &lds[(wave * 4 + i) * 512]);
        }
#pragma unroll
        for (int j = 0; j < 8; ++j) {           // B slot sid = wave*8 + j
            int u = wave * 2 + (j >> 2), s2 = (j >> 1) & 1, hl = j & 1;
            const _Float16* gp = Wp + (size_t)(blockIdx.y * 8 + u) * 16384
                               + (kc * 2 + s2) * 512 + (hl ? WOFF : 0) + lane * 8;
            GLDS16(gp, &lds[8192 + (wave * 8 + j) * 512]);
        }
        __syncthreads();                        // compiler emits vmcnt(0) drain

        // ---- compute: 2 k-steps x (2 m-tiles x 4 n-tiles) x 3 terms
#pragma unroll
        for (int s2 = 0; s2 < 2; ++s2) {
            half8 ah[2], al[2], bh[4], bl[4];
#pragma unroll
            for (int t2 = 0; t2 < 2; ++t2) {
                int t = wm * 2 + t2;
                ah[t2] = *(const half8*)&lds[((t * 2 + s2) * 2 + 0) * 512 + lane * 8];
                al[t2] = *(const half8*)&lds[((t * 2 + s2) * 2 + 1) * 512 + lane * 8];
            }
#pragma unroll
            for (int u2 = 0; u2 < 4; ++u2) {
                int u = wn * 4 + u2;
                bh[u2] = *(const half8*)&lds[8192 + ((u * 2 + s2) * 2 + 0) * 512 + lane * 8];
                bl[u2] = *(const half8*)&lds[8192 + ((u * 2 + s2) * 2 + 1) * 512 + lane * 8];
            }
#pragma unroll
            for (int t2 = 0; t2 < 2; ++t2)
#pragma unroll
                for (int u2 = 0; u2 < 4; ++u2) {
                    acc[t2][u2] = __builtin_amdgcn_mfma_f32_16x16x32_f16(ah[t2], bh[u2], acc[t2][u2], 0, 0, 0);
                    acc[t2][u2] = __builtin_amdgcn_mfma_f32_16x16x32_f16(ah[t2], bl[u2], acc[t2][u2], 0, 0, 0);
                    acc[t2][u2] = __builtin_amdgcn_mfma_f32_16x16x32_f16(al[t2], bh[u2], acc[t2][u2], 0, 0, 0);
                }
        }
        __syncthreads();                        // before next chunk overwrites
    }

    // ---- epilogue: C/D row = q*4+reg, col = r (per 16x16 tile)
#pragma unroll
    for (int t2 = 0; t2 < 2; ++t2)
#pragma unroll
        for (int reg = 0; reg < 4; ++reg) {
            int m = bm0 + (wm * 2 + t2) * 16 + q * 4 + reg;
            if (m < M) {
                int node = ((m + 1) << (h + 1)) - 2 - __popc(m);
#pragma unroll
                for (int u2 = 0; u2 < 4; ++u2) {
                    int col = bn0 + (wn * 4 + u2) * 16 + r;
                    float v = relu_f(acc[t2][u2][reg] + bW[col]);
                    _Float16 hi = (_Float16)v;
                    Hh[(size_t)node * EMBED + col] = hi;
                    Hl[(size_t)node * EMBED + col] = (_Float16)(v - (float)hi);
                }
            }
        }
}

// ---------------------------------------------------------------------------
// Small-level GEMM (M<=64): fragment-direct from global, no LDS/barriers.
__global__ __launch_bounds__(256)
void gemm_small(_Float16* Hh, _Float16* Hl,
                const _Float16* __restrict__ Whp, const _Float16* __restrict__ Wlp,
                const float* __restrict__ bW, int h, int M)
{
    int tid = threadIdx.x;
    int wave = tid >> 6, lane = tid & 63;
    int quad = lane >> 4, r = lane & 15;
    int mw = (blockIdx.x * 4 + wave) * 16;

    int m = mw + r;
    if (m >= M) m = M - 1;
    int idx = ((m + 1) << (h + 1)) - 2 - __popc(m);
    int leftRow  = idx - (1 << h);
    int rightRow = idx - 1;
    const _Float16* pLh = Hh + (size_t)leftRow  * EMBED + quad * 8;
    const _Float16* pLl = Hl + (size_t)leftRow  * EMBED + quad * 8;
    const _Float16* pRh = Hh + (size_t)rightRow * EMBED + quad * 8;
    const _Float16* pRl = Hl + (size_t)rightRow * EMBED + quad * 8;
    const _Float16* pBh = Whp + (size_t)blockIdx.y * 4 * 16384 + lane * 8;
    const _Float16* pBl = Wlp + (size_t)blockIdx.y * 4 * 16384 + lane * 8;

    floatx4 acc[4];
#pragma unroll
    for (int nt = 0; nt < 4; ++nt) acc[nt] = (floatx4){0.f, 0.f, 0.f, 0.f};

#pragma unroll 4
    for (int s = 0; s < 32; ++s) {
        int k0 = s * 32;
        const _Float16* ah_p = (s < 16) ? (pLh + k0) : (pRh + k0 - EMBED);
        const _Float16* al_p = (s < 16) ? (pLl + k0) : (pRl + k0 - EMBED);
        half8 ah = *(const half8*)ah_p;
        half8 al = *(const half8*)al_p;
#pragma unroll
        for (int nt = 0; nt < 4; ++nt) {
            half8 bh = *(const half8*)(pBh + nt * 16384 + s * 512);
            half8 bl = *(const half8*)(pBl + nt * 16384 + s * 512);
            acc[nt] = __builtin_amdgcn_mfma_f32_16x16x32_f16(ah, bh, acc[nt], 0, 0, 0);
            acc[nt] = __builtin_amdgcn_mfma_f32_16x16x32_f16(ah, bl, acc[nt], 0, 0, 0);
            acc[nt] = __builtin_amdgcn_mfma_f32_16x16x32_f16(al, bh, acc[nt], 0, 0, 0);
        }
    }

    int n0 = blockIdx.y * 64;
#pragma unroll
    for (int nt = 0; nt < 4; ++nt) {
        int col = n0 + nt * 16 + r;
        float bw = bW[col];
#pragma unroll
        for (int reg = 0; reg < 4; ++reg) {
            int mm = mw + quad * 4 + reg;
            if (mm < M) {
                float v = relu_f(acc[nt][reg] + bw);
                _Float16 hi = (_Float16)v;
                _Float16 lo = (_Float16)(v - (float)hi);
                int nodeIdx = ((mm + 1) << (h + 1)) - 2 - __popc(mm);
                Hh[(size_t)nodeIdx * EMBED + col] = hi;
                Hl[(size_t)nodeIdx * EMBED + col] = lo;
            }
        }
    }
}

// ---------------------------------------------------------------------------
__global__ __launch_bounds__(256)
void out_kernel(const _Float16* __restrict__ Hh, const _Float16* __restrict__ Hl,
                const float* __restrict__ P, const float* __restrict__ bP,
                float* __restrict__ out, int nNodes)
{
    int t = blockIdx.x * 256 + threadIdx.x;
    int node = t >> 6, lane = t & 63;
    if (node >= nNodes) return;
    half8 hv = *(const half8*)(Hh + (size_t)node * EMBED + lane * 8);
    half8 lv = *(const half8*)(Hl + (size_t)node * EMBED + lane * 8);
    float hx[8];
#pragma unroll
    for (int j = 0; j < 8; ++j) hx[j] = (float)hv[j] + (float)lv[j];
    float s[5];
#pragma unroll
    for (int c = 0; c < 5; ++c) {
        const float* p = P + c * EMBED + lane * 8;
        float4 p0 = *(const float4*)p;
        float4 p1 = *(const float4*)(p + 4);
        s[c] = hx[0] * p0.x + hx[1] * p0.y + hx[2] * p0.z + hx[3] * p0.w
             + hx[4] * p1.x + hx[5] * p1.y + hx[6] * p1.z + hx[7] * p1.w;
    }
#pragma unroll
    for (int o = 32; o > 0; o >>= 1)
#pragma unroll
        for (int c = 0; c < 5; ++c)
            s[c] += __shfl_down(s[c], o, 64);
    if (lane == 0) {
#pragma unroll
        for (int c = 0; c < 5; ++c)
            out[(size_t)node * 5 + c] = s[c] + bP[c];
    }
}

// ---------------------------------------------------------------------------
extern "C" void kernel_launch(void* const* d_in, const int* in_sizes, int n_in,
                              void* d_out, int out_size, void* d_ws, size_t ws_size,
                              hipStream_t stream)
{
    const int*   word = (const int*)d_in[1];
    const float* emb  = (const float*)d_in[4];
    const float* W    = (const float*)d_in[5];
    const float* bW   = (const float*)d_in[6];
    const float* P    = (const float*)d_in[7];
    const float* bP   = (const float*)d_in[8];
    float* out = (float*)d_out;

    int nNodes  = in_sizes[0];            // 16383
    int nLeaves = (nNodes + 1) / 2;       // 8192
    int L = 0;
    while ((1 << L) < nLeaves) ++L;       // 13

    int hoff = (nNodes + 1) * EMBED;      // halves between Hh and Hl
    _Float16* Hh  = (_Float16*)d_ws;
    _Float16* Hl  = Hh + hoff;
    _Float16* Whp = Hl + hoff;
    _Float16* Wlp = Whp + WOFF;           // contiguous: Wlp = Whp + WOFF

    pack_w<<<dim3(256), dim3(256), 0, stream>>>(W, Whp, Wlp);
    leaf_kernel<<<dim3((nLeaves * 64 + 255) / 256), dim3(256), 0, stream>>>(
        emb, word, Hh, Hl, nLeaves);
    for (int h = 1; h <= L; ++h) {
        int M = 1 << (L - h);
        if (M >= 128) {
            gemm_big<<<dim3(M / 64, 4), dim3(256), 0, stream>>>(
                Hh, Whp, bW, Hh, Hl, h, M, hoff);
        } else {
            gemm_small<<<dim3((M + 63) / 64, 8), dim3(256), 0, stream>>>(
                Hh, Hl, Whp, Wlp, bW, h, M);
        }
    }
    out_kernel<<<dim3((nNodes * 64 + 255) / 256), dim3(256), 0, stream>>>(
        Hh, Hl, P, bP, out, nNodes);
}

// Round 4
// 284.041 us; speedup vs baseline: 3.4607x; 1.7018x over previous
//
#include <hip/hip_runtime.h>

// RecursiveNN, perfect binary tree, 8192 leaves, EMBED=512.
// Closed-form post-order indexing: node at height h, position m:
//   idx = ((m+1)<<(h+1)) - 2 - popc(m);  left = idx - (1<<h);  right = idx - 1
// Numerics: fp16 hi+lo split H and W; 3-term MFMA (hh, hl, lh) => ~fp32 accuracy.
// Levels h=1..4 (M>=512): LDS-staged GEMM (global_load_lds w=16), 64x128 block.
// Levels h>=5 (M<=256): split-K kernel — block = 16x16 output tile, 4 waves
//   split K=1024 into 256-slices, LDS fp32 reduce + fused epilogue. This keeps
//   hundreds of waves in flight so the ~2MB W fetch is latency-covered
//   (round-3 gemm_small: 32 waves -> 44 us/level at 51 GB/s, pure latency).

#define EMBED 512
#define K2    1024
#define WOFF  (EMBED * K2)   // halves between Whp and Wlp (contiguous)

typedef _Float16 half8 __attribute__((ext_vector_type(8)));
typedef float    floatx4 __attribute__((ext_vector_type(4)));

__device__ __forceinline__ float relu_f(float x) { return fmaxf(x, 0.0f); }

#define GLDS16(gp, lp)                                                        \
    __builtin_amdgcn_global_load_lds(                                         \
        (const __attribute__((address_space(1))) void*)(gp),                  \
        (__attribute__((address_space(3))) void*)(lp), 16, 0, 0)

// ---------------------------------------------------------------------------
// Split W (512x1024 f32) into fp16 hi/lo, packed in MFMA-B fragment order:
// for n-tile T (16 cols), k-step S (32 k): 1 KB contiguous at
// T*16384 + S*512 + lane*8, lane = ((k>>3)&3)<<4 | (n&15).
__global__ __launch_bounds__(256)
void pack_w(const float* __restrict__ W,
            _Float16* __restrict__ Whp, _Float16* __restrict__ Wlp)
{
    int t = blockIdx.x * 256 + threadIdx.x;      // 65536 threads
    int n = t >> 7, kc = t & 127;                // kc: chunk of 8 k
    const float* src = W + (size_t)n * K2 + kc * 8;
    int s = kc >> 2, quad = kc & 3;
    int lane = (quad << 4) | (n & 15);
    size_t off = (size_t)(n >> 4) * 16384 + (size_t)s * 512 + (size_t)lane * 8;
    half8 hi, lo;
#pragma unroll
    for (int j = 0; j < 8; ++j) {
        float w = src[j];
        _Float16 h = (_Float16)w;
        hi[j] = h;
        lo[j] = (_Float16)(w - (float)h);
    }
    *(half8*)(Whp + off) = hi;
    *(half8*)(Wlp + off) = lo;
}

// ---------------------------------------------------------------------------
__global__ __launch_bounds__(256)
void leaf_kernel(const float* __restrict__ emb, const int* __restrict__ word,
                 _Float16* __restrict__ Hh, _Float16* __restrict__ Hl, int nLeaves)
{
    int t = blockIdx.x * 256 + threadIdx.x;
    int m = t >> 6, lane = t & 63;
    if (m >= nLeaves) return;
    int idx = 2 * m - __popc(m);
    int wd = word[idx];
    const float4* src = (const float4*)(emb + (size_t)wd * EMBED) + lane * 2;
    float4 a = src[0], b = src[1];
    float v[8] = {a.x, a.y, a.z, a.w, b.x, b.y, b.z, b.w};
    half8 hi, lo;
#pragma unroll
    for (int j = 0; j < 8; ++j) {
        float x = relu_f(v[j]);
        _Float16 h = (_Float16)x;
        hi[j] = h;
        lo[j] = (_Float16)(x - (float)h);
    }
    *(half8*)(Hh + (size_t)idx * EMBED + lane * 8) = hi;
    *(half8*)(Hl + (size_t)idx * EMBED + lane * 8) = lo;
}

// ---------------------------------------------------------------------------
// Big-level GEMM (M>=512). Block 64 rows x 128 cols, 4 waves 2x2, LDS-staged
// fragments via global_load_lds w=16; 3-term split-fp16 MFMA.
__global__ __launch_bounds__(256)
void gemm_big(const _Float16* H,            // Hh base; Hl = H + hoff
              const _Float16* __restrict__ Wp,  // Whp; Wlp = Wp + WOFF
              const float* __restrict__ bW,
              _Float16* Hh, _Float16* Hl,
              int h, int M, int hoff)
{
    __shared__ _Float16 lds[48 * 512];          // 48 KB

    int tid = threadIdx.x;
    int wave = tid >> 6, lane = tid & 63;
    int q = lane >> 4, r = lane & 15;
    int wm = wave >> 1, wn = wave & 1;
    int bm0 = blockIdx.x * 64, bn0 = blockIdx.y * 128;

    int ms = bm0 + wave * 16 + r;
    if (ms >= M) ms = M - 1;
    int node_s = ((ms + 1) << (h + 1)) - 2 - __popc(ms);
    int aL = (node_s - (1 << h)) * EMBED + q * 8;
    int aR = (node_s - 1) * EMBED + q * 8;

    floatx4 acc[2][4];
#pragma unroll
    for (int i = 0; i < 2; ++i)
#pragma unroll
        for (int j = 0; j < 4; ++j) acc[i][j] = (floatx4){0.f, 0.f, 0.f, 0.f};

    for (int kc = 0; kc < 16; ++kc) {
        int abase = (kc < 8) ? (aL + kc * 64) : (aR + (kc - 8) * 64);
#pragma unroll
        for (int i = 0; i < 4; ++i) {           // i = s2*2 + hl
            int s2 = i >> 1, hl = i & 1;
            const _Float16* gp = H + abase + s2 * 32 + (hl ? hoff : 0);
            GLDS16(gp, &lds[(wave * 4 + i) * 512]);
        }
#pragma unroll
        for (int j = 0; j < 8; ++j) {           // B slot sid = wave*8 + j
            int u = wave * 2 + (j >> 2), s2 = (j >> 1) & 1, hl = j & 1;
            const _Float16* gp = Wp + (size_t)(blockIdx.y * 8 + u) * 16384
                               + (kc * 2 + s2) * 512 + (hl ? WOFF : 0) + lane * 8;
            GLDS16(gp, &lds[8192 + (wave * 8 + j) * 512]);
        }
        __syncthreads();

#pragma unroll
        for (int s2 = 0; s2 < 2; ++s2) {
            half8 ah[2], al[2], bh[4], bl[4];
#pragma unroll
            for (int t2 = 0; t2 < 2; ++t2) {
                int t = wm * 2 + t2;
                ah[t2] = *(const half8*)&lds[((t * 2 + s2) * 2 + 0) * 512 + lane * 8];
                al[t2] = *(const half8*)&lds[((t * 2 + s2) * 2 + 1) * 512 + lane * 8];
            }
#pragma unroll
            for (int u2 = 0; u2 < 4; ++u2) {
                int u = wn * 4 + u2;
                bh[u2] = *(const half8*)&lds[8192 + ((u * 2 + s2) * 2 + 0) * 512 + lane * 8];
                bl[u2] = *(const half8*)&lds[8192 + ((u * 2 + s2) * 2 + 1) * 512 + lane * 8];
            }
#pragma unroll
            for (int t2 = 0; t2 < 2; ++t2)
#pragma unroll
                for (int u2 = 0; u2 < 4; ++u2) {
                    acc[t2][u2] = __builtin_amdgcn_mfma_f32_16x16x32_f16(ah[t2], bh[u2], acc[t2][u2], 0, 0, 0);
                    acc[t2][u2] = __builtin_amdgcn_mfma_f32_16x16x32_f16(ah[t2], bl[u2], acc[t2][u2], 0, 0, 0);
                    acc[t2][u2] = __builtin_amdgcn_mfma_f32_16x16x32_f16(al[t2], bh[u2], acc[t2][u2], 0, 0, 0);
                }
        }
        __syncthreads();
    }

#pragma unroll
    for (int t2 = 0; t2 < 2; ++t2)
#pragma unroll
        for (int reg = 0; reg < 4; ++reg) {
            int m = bm0 + (wm * 2 + t2) * 16 + q * 4 + reg;
            if (m < M) {
                int node = ((m + 1) << (h + 1)) - 2 - __popc(m);
#pragma unroll
                for (int u2 = 0; u2 < 4; ++u2) {
                    int col = bn0 + (wn * 4 + u2) * 16 + r;
                    float v = relu_f(acc[t2][u2][reg] + bW[col]);
                    _Float16 hi = (_Float16)v;
                    Hh[(size_t)node * EMBED + col] = hi;
                    Hl[(size_t)node * EMBED + col] = (_Float16)(v - (float)hi);
                }
            }
        }
}

// ---------------------------------------------------------------------------
// Small-level split-K kernel (M<=256). Block = one 16x16 output tile;
// 4 waves each own a K=256 slice (8 k-steps x 3-term MFMA), fp32 partials
// reduced via LDS, fused bias+relu+split epilogue. grid = (ceil(M/16), 32).
__global__ __launch_bounds__(256)
void gemm_splitk(const _Float16* __restrict__ Hh, const _Float16* __restrict__ Hl,
                 const _Float16* __restrict__ Wp,   // Whp; Wlp = Wp + WOFF
                 const float* __restrict__ bW,
                 _Float16* HhO, _Float16* HlO,
                 int h, int M)
{
    __shared__ float red[4 * 256];

    int tid = threadIdx.x;
    int wave = tid >> 6, lane = tid & 63;
    int q = lane >> 4, r = lane & 15;
    int mt = blockIdx.x, u = blockIdx.y;

    int m = mt * 16 + r;
    if (m >= M) m = M - 1;
    int idx = ((m + 1) << (h + 1)) - 2 - __popc(m);
    // wave k-slice: global k in [wave*256, wave*256+256)
    int childRow = (wave < 2) ? (idx - (1 << h)) : (idx - 1);
    int kbase = (wave & 1) * 256;                // offset within child row
    const _Float16* pAh = Hh + (size_t)childRow * EMBED + kbase + q * 8;
    const _Float16* pAl = Hl + (size_t)childRow * EMBED + kbase + q * 8;
    const _Float16* pB  = Wp + (size_t)u * 16384 + (size_t)(wave * 8) * 512 + lane * 8;

    floatx4 acc = (floatx4){0.f, 0.f, 0.f, 0.f};
#pragma unroll
    for (int s = 0; s < 8; ++s) {
        half8 ah = *(const half8*)(pAh + s * 32);
        half8 al = *(const half8*)(pAl + s * 32);
        half8 bh = *(const half8*)(pB + s * 512);
        half8 bl = *(const half8*)(pB + s * 512 + WOFF);
        acc = __builtin_amdgcn_mfma_f32_16x16x32_f16(ah, bh, acc, 0, 0, 0);
        acc = __builtin_amdgcn_mfma_f32_16x16x32_f16(ah, bl, acc, 0, 0, 0);
        acc = __builtin_amdgcn_mfma_f32_16x16x32_f16(al, bh, acc, 0, 0, 0);
    }
    // partials: C/D layout row = q*4+reg, col = r
#pragma unroll
    for (int reg = 0; reg < 4; ++reg)
        red[wave * 256 + (q * 4 + reg) * 16 + r] = acc[reg];
    __syncthreads();

    // 256 threads = 16x16 outputs: tid -> (row, col)
    int row = tid >> 4, col = tid & 15;
    float v = red[row * 16 + col] + red[256 + row * 16 + col]
            + red[512 + row * 16 + col] + red[768 + row * 16 + col];
    int mm = mt * 16 + row;
    if (mm < M) {
        int node = ((mm + 1) << (h + 1)) - 2 - __popc(mm);
        int colg = u * 16 + col;
        float x = relu_f(v + bW[colg]);
        _Float16 hi = (_Float16)x;
        HhO[(size_t)node * EMBED + colg] = hi;
        HlO[(size_t)node * EMBED + colg] = (_Float16)(x - (float)hi);
    }
}

// ---------------------------------------------------------------------------
__global__ __launch_bounds__(256)
void out_kernel(const _Float16* __restrict__ Hh, const _Float16* __restrict__ Hl,
                const float* __restrict__ P, const float* __restrict__ bP,
                float* __restrict__ out, int nNodes)
{
    int t = blockIdx.x * 256 + threadIdx.x;
    int node = t >> 6, lane = t & 63;
    if (node >= nNodes) return;
    half8 hv = *(const half8*)(Hh + (size_t)node * EMBED + lane * 8);
    half8 lv = *(const half8*)(Hl + (size_t)node * EMBED + lane * 8);
    float hx[8];
#pragma unroll
    for (int j = 0; j < 8; ++j) hx[j] = (float)hv[j] + (float)lv[j];
    float s[5];
#pragma unroll
    for (int c = 0; c < 5; ++c) {
        const float* p = P + c * EMBED + lane * 8;
        float4 p0 = *(const float4*)p;
        float4 p1 = *(const float4*)(p + 4);
        s[c] = hx[0] * p0.x + hx[1] * p0.y + hx[2] * p0.z + hx[3] * p0.w
             + hx[4] * p1.x + hx[5] * p1.y + hx[6] * p1.z + hx[7] * p1.w;
    }
#pragma unroll
    for (int o = 32; o > 0; o >>= 1)
#pragma unroll
        for (int c = 0; c < 5; ++c)
            s[c] += __shfl_down(s[c], o, 64);
    if (lane == 0) {
#pragma unroll
        for (int c = 0; c < 5; ++c)
            out[(size_t)node * 5 + c] = s[c] + bP[c];
    }
}

// ---------------------------------------------------------------------------
extern "C" void kernel_launch(void* const* d_in, const int* in_sizes, int n_in,
                              void* d_out, int out_size, void* d_ws, size_t ws_size,
                              hipStream_t stream)
{
    const int*   word = (const int*)d_in[1];
    const float* emb  = (const float*)d_in[4];
    const float* W    = (const float*)d_in[5];
    const float* bW   = (const float*)d_in[6];
    const float* P    = (const float*)d_in[7];
    const float* bP   = (const float*)d_in[8];
    float* out = (float*)d_out;

    int nNodes  = in_sizes[0];            // 16383
    int nLeaves = (nNodes + 1) / 2;       // 8192
    int L = 0;
    while ((1 << L) < nLeaves) ++L;       // 13

    int hoff = (nNodes + 1) * EMBED;      // halves between Hh and Hl
    _Float16* Hh  = (_Float16*)d_ws;
    _Float16* Hl  = Hh + hoff;
    _Float16* Whp = Hl + hoff;

    pack_w<<<dim3(256), dim3(256), 0, stream>>>(W, Whp, Whp + WOFF);
    leaf_kernel<<<dim3((nLeaves * 64 + 255) / 256), dim3(256), 0, stream>>>(
        emb, word, Hh, Hl, nLeaves);
    for (int h = 1; h <= L; ++h) {
        int M = 1 << (L - h);
        if (M >= 512) {
            gemm_big<<<dim3(M / 64, 4), dim3(256), 0, stream>>>(
                Hh, Whp, bW, Hh, Hl, h, M, hoff);
        } else {
            gemm_splitk<<<dim3((M + 15) / 16, 32), dim3(256), 0, stream>>>(
                Hh, Hl, Whp, bW, Hh, Hl, h, M);
        }
    }
    out_kernel<<<dim3((nNodes * 64 + 255) / 256), dim3(256), 0, stream>>>(
        Hh, Hl, P, bP, out, nNodes);
}